// Round 18
// baseline (169.438 us; speedup 1.0000x reference)
//
#include <hip/hip_runtime.h>
#include <hip/hip_bf16.h>

#define N_NODES 50000
#define NIN 512
#define NH 96
#define NL 32
#define NH2 64

#define NB2 196          // coarse buckets of 256 nodes
#define NBLK 128         // binning blocks
#define BCAP 5120        // fixed region capacity per bucket (E[cnt]=4096, +16 sigma)

typedef __attribute__((ext_vector_type(8))) short short8v;   // 8 bf16 (4 VGPR)
typedef __attribute__((ext_vector_type(4))) float f32x4;

__device__ __forceinline__ unsigned short f2bf(float f) {    // RNE via native cvt
    __hip_bfloat16 h = __float2bfloat16(f);
    unsigned short u;
    __builtin_memcpy(&u, &h, 2);
    return u;
}
__device__ __forceinline__ float bf2f(unsigned short h) {
    return __uint_as_float((unsigned)h << 16);
}

// fused: WbT = W1^T bf16; W2T = [Wmu|Wls]^T bf16; gcur = 0
__global__ __launch_bounds__(256) void k_prep(const float* __restrict__ W1,
                                              const float* __restrict__ Wmu,
                                              const float* __restrict__ Wls,
                                              unsigned short* __restrict__ WbT,
                                              unsigned short* __restrict__ W2T,
                                              int* __restrict__ gcur) {
    int idx = blockIdx.x * 256 + threadIdx.x;
    if (idx < NH * NIN) {
        int n = idx >> 9, k = idx & 511;
        WbT[idx] = f2bf(W1[(size_t)k * NH + n]);
    } else if (idx < NH * NIN + NH2 * NH) {
        int j = idx - NH * NIN;
        int n = j / NH, k = j - n * NH;
        float v = (n < NL) ? Wmu[k * NL + n] : Wls[k * NL + (n - NL)];
        W2T[j] = f2bf(v);
    }
    if (idx < NB2) gcur[idx] = 0;
}

// pass A: privatized block-run binning into fixed-capacity bucket regions.
// Runs contiguous -> each cache line owned by one block/XCD (r14 lesson).
__global__ __launch_bounds__(256) void k_coarse(const int* __restrict__ src,
                                                const int* __restrict__ dst,
                                                int* __restrict__ gcur,
                                                unsigned* __restrict__ cpair, int E) {
    __shared__ int hist[NB2];
    __shared__ int lpos[NB2];
    int t = threadIdx.x;
    int ch = (E + NBLK - 1) / NBLK;
    int e0 = blockIdx.x * ch, e1 = min(e0 + ch, E);
    for (int b = t; b < NB2; b += 256) hist[b] = 0;
    __syncthreads();
    for (int e = e0 + t; e < e1; e += 256)
        atomicAdd(&hist[dst[e] >> 8], 1);
    __syncthreads();
    for (int b = t; b < NB2; b += 256) {
        int cnt = hist[b];
        int base = (cnt > 0) ? atomicAdd(&gcur[b], cnt) : 0;
        lpos[b] = b * BCAP + base;
    }
    __syncthreads();
    for (int e = e0 + t; e < e1; e += 256) {
        int s = src[e], d = dst[e];
        int pos = atomicAdd(&lpos[d >> 8], 1);
        cpair[pos] = (unsigned)s | ((unsigned)d << 16);
    }
}

// pass B: one block per bucket. Computes its own global base (LDS reduce over
// gcur[0..bb-1] -- k_bscan deleted), derives per-node counts + rowoff + dis,
// then places edges into the bucket's private esrc window.
__global__ __launch_bounds__(256) void k_fine(const unsigned* __restrict__ cpair,
                                              const int* __restrict__ gcur,
                                              int* __restrict__ rowoff,
                                              float* __restrict__ dis,
                                              int* __restrict__ esrc) {
    __shared__ int lcnt[256];
    __shared__ int lscan[256];
    int bb = blockIdx.x;
    int n0 = bb << 8;
    int t = threadIdx.x;
    // base = sum gcur[0..bb-1]
    lscan[t] = (t < bb) ? gcur[t] : 0;
    __syncthreads();
    for (int off = 128; off > 0; off >>= 1) {
        if (t < off) lscan[t] += lscan[t + off];
        __syncthreads();
    }
    int base = lscan[0];
    if (bb == NB2 - 1 && t == 0) rowoff[N_NODES] = base + gcur[bb];
    lcnt[t] = 0;
    __syncthreads();                      // also fences the lscan reuse below
    int p0 = bb * BCAP;
    int p1 = p0 + gcur[bb];
    for (int p = p0 + t; p < p1; p += 256)
        atomicAdd(&lcnt[(cpair[p] >> 16) - n0], 1);
    __syncthreads();
    int cnt = lcnt[t];
    lscan[t] = cnt;
    __syncthreads();
    for (int off = 1; off < 256; off <<= 1) {
        int u = (t >= off) ? lscan[t - off] : 0;
        __syncthreads();
        lscan[t] += u;
        __syncthreads();
    }
    int excl = lscan[t] - cnt;
    int node = n0 + t;
    if (node < N_NODES) {
        rowoff[node] = base + excl;
        dis[node] = rsqrtf((float)cnt + 1.0f);
    }
    lcnt[t] = base + excl;                // running absolute position
    __syncthreads();
    for (int p = p0 + t; p < p1; p += 256) {
        unsigned u = cpair[p];
        int d = (int)(u >> 16);
        int pos = atomicAdd(&lcnt[d - n0], 1);
        esrc[pos] = (int)(u & 0xFFFFu);
    }
}

// h' = (x @ W1) * dis[row], bf16 MFMA 16x16x32 (r16 measured-best config).
// BM=64 (4 waves x 16 rows), BK=64, 8 K-tiles -> 782 blocks = 3 blocks/CU.
// LDS rows 128B, slot ^= (row&7): conflict-free frag reads, coalesced staging.
#define GBM 64
__global__ __launch_bounds__(256, 3) void k_gemm1(const float* __restrict__ x,
                                                  const unsigned short* __restrict__ WbT,
                                                  const float* __restrict__ dis,
                                                  unsigned short* __restrict__ hb, int M) {
    __shared__ __align__(16) char lA[64 * 128];    // 8 KB
    __shared__ __align__(16) char lB[96 * 128];    // 12 KB
    int tid = threadIdx.x;
    int lane = tid & 63, w = tid >> 6;
    int l15 = lane & 15, hi = lane >> 4;
    int m0 = blockIdx.x * GBM;

    f32x4 acc[6];
#pragma unroll
    for (int nt = 0; nt < 6; ++nt)
#pragma unroll
        for (int i = 0; i < 4; ++i) acc[nt][i] = 0.f;

    int key = l15 & 7;
    int arow = (w * 16 + l15) * 128;

    for (int kt = 0; kt < 8; ++kt) {
        __syncthreads();
#pragma unroll
        for (int i = 0; i < 2; ++i) {      // A: 512 slots (64 rows x 8), 2/thread
            int s = i * 256 + tid;
            int r = s >> 3, sl = s & 7;
            const float* p = x + (size_t)min(m0 + r, M - 1) * NIN + kt * 64 + sl * 8;
            float4 a0 = *reinterpret_cast<const float4*>(p);
            float4 a1 = *reinterpret_cast<const float4*>(p + 4);
            uint4 pk;
            pk.x = (unsigned)f2bf(a0.x) | ((unsigned)f2bf(a0.y) << 16);
            pk.y = (unsigned)f2bf(a0.z) | ((unsigned)f2bf(a0.w) << 16);
            pk.z = (unsigned)f2bf(a1.x) | ((unsigned)f2bf(a1.y) << 16);
            pk.w = (unsigned)f2bf(a1.z) | ((unsigned)f2bf(a1.w) << 16);
            *reinterpret_cast<uint4*>(lA + r * 128 + ((sl ^ (r & 7)) << 4)) = pk;
        }
#pragma unroll
        for (int i = 0; i < 3; ++i) {      // B: 768 slots (96 rows x 8), 3/thread
            int s = i * 256 + tid;
            int n = s >> 3, sl = s & 7;
            uint4 bv = *reinterpret_cast<const uint4*>(WbT + (size_t)n * NIN + kt * 64 + sl * 8);
            *reinterpret_cast<uint4*>(lB + n * 128 + ((sl ^ (n & 7)) << 4)) = bv;
        }
        __syncthreads();

#pragma unroll
        for (int kc = 0; kc < 2; ++kc) {
            int off = (((kc * 4 + hi) ^ key) << 4);
            short8v a = *reinterpret_cast<const short8v*>(lA + arow + off);
#pragma unroll
            for (int nt = 0; nt < 6; ++nt) {
                short8v bv = *reinterpret_cast<const short8v*>(lB + (nt * 16 + l15) * 128 + off);
                acc[nt] = __builtin_amdgcn_mfma_f32_16x16x32_bf16(a, bv, acc[nt], 0, 0, 0);
            }
        }
    }

    // C: row=(lane>>4)*4+reg, col=lane&15 (m89-verified); fuse dis scale, bf16 out
    int rbase = m0 + w * 16 + hi * 4;
#pragma unroll
    for (int r = 0; r < 4; ++r) {
        int orow = rbase + r;
        if (orow < M) {
            float dv = dis[orow];
            unsigned short* op = hb + (size_t)orow * NH + l15;
#pragma unroll
            for (int nt = 0; nt < 6; ++nt) op[nt * 16] = f2bf(acc[nt][r] * dv);
        }
    }
}

// FUSED gather1 + gemm2: 64 nodes/block. 8x32-lane groups aggregate h' rows,
// apply relu((acc+self)*dis+b1), and store hid as bf16 DIRECTLY INTO LDS at
// the XOR-swizzled layout the MFMA frag-reads expect (write key r&7 == read
// key l15&7 since rows r, r+8 share &7; <=2-way bank aliasing = free). Then
// one barrier and the verified gemm2 body computes h23 = (hid @ W2) * dis.
// Deletes the hid global round-trip + the separate gemm2 launch.
#define FB 64
__global__ __launch_bounds__(256) void k_g1g2(const ushort4* __restrict__ hb4,
                                              const int* __restrict__ rowoff,
                                              const int* __restrict__ esrc,
                                              const float* __restrict__ dis,
                                              const float* __restrict__ b1,
                                              const unsigned short* __restrict__ W2T,
                                              unsigned short* __restrict__ h23, int M) {
    __shared__ __align__(16) char lA[64 * 256];    // hid bf16, 12/16 slots used
    __shared__ __align__(16) char lB[64 * 256];    // W2T
    int tid = threadIdx.x;
    int g = tid >> 5, c = tid & 31;
    int m0 = blockIdx.x * FB;

    // stage B (W2T): 64 rows x 12 slots = 768, 3/thread, coalesced
#pragma unroll
    for (int i = 0; i < 3; ++i) {
        int s = i * 256 + tid;
        int n = s / 12, sl = s - n * 12;
        uint4 v = *reinterpret_cast<const uint4*>(W2T + (size_t)n * NH + sl * 8);
        *reinterpret_cast<uint4*>(lB + n * 256 + ((sl ^ (n & 7)) << 4)) = v;
    }

    bool act = (c < 24);
    float4 bv4 = act ? reinterpret_cast<const float4*>(b1)[c]
                     : make_float4(0.f, 0.f, 0.f, 0.f);

    for (int it = 0; it < 8; ++it) {
        int node = m0 + g * 8 + it;
        int nd = min(node, M - 1);             // no early return: MFMA needs all threads
        int p0 = rowoff[nd], p1 = rowoff[nd + 1];
        float ax = 0.f, ay = 0.f, az = 0.f, aw = 0.f;
        for (int pb = p0; pb < p1; pb += 32) {
            int nb = min(32, p1 - pb);
            int sv = (c < nb) ? esrc[pb + c] : 0;
#pragma unroll 4
            for (int j = 0; j < nb; j++) {
                int s = __shfl(sv, j, 32);
                if (act) {
                    ushort4 v = hb4[(size_t)s * 24 + c];
                    ax += bf2f(v.x); ay += bf2f(v.y); az += bf2f(v.z); aw += bf2f(v.w);
                }
            }
        }
        if (act) {
            float dv = dis[nd];
            ushort4 hv = hb4[(size_t)nd * 24 + c];
            ushort4 o;
            o.x = f2bf(fmaxf((ax + bf2f(hv.x)) * dv + bv4.x, 0.f));
            o.y = f2bf(fmaxf((ay + bf2f(hv.y)) * dv + bv4.y, 0.f));
            o.z = f2bf(fmaxf((az + bf2f(hv.z)) * dv + bv4.z, 0.f));
            o.w = f2bf(fmaxf((aw + bf2f(hv.w)) * dv + bv4.w, 0.f));
            int r = g * 8 + it;
            int sl = c >> 1;
            *reinterpret_cast<ushort4*>(
                lA + r * 256 + (((sl ^ (r & 7))) << 4) + (c & 1) * 8) = o;
        }
    }
    __syncthreads();

    // gemm2 phase (verified r17 body, A already staged in LDS)
    int lane = tid & 63, w4 = tid >> 6;
    int l15 = lane & 15, hi = lane >> 4, key = l15 & 7;
    f32x4 acc[4];
#pragma unroll
    for (int nt = 0; nt < 4; ++nt)
#pragma unroll
        for (int i = 0; i < 4; ++i) acc[nt][i] = 0.f;
    const char* aptr = lA + (w4 * 16 + l15) * 256;
#pragma unroll
    for (int kc = 0; kc < 3; ++kc) {
        int off = (((kc * 4 + hi) ^ key) << 4);
        short8v a = *reinterpret_cast<const short8v*>(aptr + off);
#pragma unroll
        for (int nt = 0; nt < 4; ++nt) {
            short8v bb = *reinterpret_cast<const short8v*>(lB + (nt * 16 + l15) * 256 + off);
            acc[nt] = __builtin_amdgcn_mfma_f32_16x16x32_bf16(a, bb, acc[nt], 0, 0, 0);
        }
    }
    int rbase = m0 + w4 * 16 + hi * 4;
#pragma unroll
    for (int r = 0; r < 4; ++r) {
        int orow = rbase + r;
        if (orow < M) {
            float dv = dis[orow];
            unsigned short* op = h23 + (size_t)orow * NH2 + l15;
#pragma unroll
            for (int nt = 0; nt < 4; ++nt) op[nt * 16] = f2bf(acc[nt][r] * dv);
        }
    }
}

// gather layer 2 (bf16 rows, 128B): out = (sum h23'[s] + h23'[i]) * dis + bias
__global__ __launch_bounds__(256) void k_gather2(const ushort4* __restrict__ hb4,
                                                 const int* __restrict__ rowoff,
                                                 const int* __restrict__ esrc,
                                                 const float* __restrict__ dis,
                                                 const float* __restrict__ bmu,
                                                 const float* __restrict__ bls,
                                                 float4* __restrict__ out4) {
    int tid = threadIdx.x;
    int node = blockIdx.x * 16 + (tid >> 4);
    int c = tid & 15;
    if (node >= N_NODES) return;
    int p0 = rowoff[node], p1 = rowoff[node + 1];
    float ax = 0.f, ay = 0.f, az = 0.f, aw = 0.f;
    for (int pb = p0; pb < p1; pb += 16) {
        int nb = min(16, p1 - pb);
        int sv = (c < nb) ? esrc[pb + c] : 0;
#pragma unroll 4
        for (int j = 0; j < nb; j++) {
            int s = __shfl(sv, j, 16);
            ushort4 v = hb4[(size_t)s * 16 + c];
            ax += bf2f(v.x); ay += bf2f(v.y); az += bf2f(v.z); aw += bf2f(v.w);
        }
    }
    float dv = dis[node];
    ushort4 hv = hb4[(size_t)node * 16 + c];
    float4 bv = (c < 8) ? reinterpret_cast<const float4*>(bmu)[c]
                        : reinterpret_cast<const float4*>(bls)[c - 8];
    float4 o;
    o.x = (ax + bf2f(hv.x)) * dv + bv.x;
    o.y = (ay + bf2f(hv.y)) * dv + bv.y;
    o.z = (az + bf2f(hv.z)) * dv + bv.z;
    o.w = (aw + bf2f(hv.w)) * dv + bv.w;
    if (c < 8) out4[(size_t)node * 8 + c] = o;
    else       out4[(size_t)N_NODES * 8 + (size_t)node * 8 + (c - 8)] = o;
}

extern "C" void kernel_launch(void* const* d_in, const int* in_sizes, int n_in,
                              void* d_out, int out_size, void* d_ws, size_t ws_size,
                              hipStream_t stream) {
    const float* x   = (const float*)d_in[0];
    const float* W1  = (const float*)d_in[1];
    const float* b1  = (const float*)d_in[2];
    const float* Wmu = (const float*)d_in[3];
    const float* bmu = (const float*)d_in[4];
    const float* Wls = (const float*)d_in[5];
    const float* bls = (const float*)d_in[6];
    const int*   ei  = (const int*)d_in[7];
    int E = in_sizes[7] / 2;
    const int* src  = ei;
    const int* dstp = ei + E;

    char* w = (char*)d_ws;
    int* rowoff  = (int*)w;            w += ((size_t)N_NODES + 4) * 4;
    float* dis   = (float*)w;          w += (size_t)N_NODES * 4;
    int* gcur    = (int*)w;            w += ((size_t)NB2 + 4) * 4;
    int* esrc    = (int*)w;            w += (size_t)E * 4;
    unsigned* cpair = (unsigned*)w;    w += (size_t)NB2 * BCAP * 4;
    unsigned short* WbT  = (unsigned short*)w;  w += (size_t)NH * NIN * 2;
    unsigned short* W2T  = (unsigned short*)w;  w += (size_t)NH2 * NH * 2;
    unsigned short* hbuf = (unsigned short*)w;  w += (size_t)N_NODES * NH * 2;
    unsigned short* h23  = (unsigned short*)w;  w += (size_t)N_NODES * NH2 * 2;

    int prep_n = NH * NIN + NH2 * NH;
    k_prep<<<(prep_n + 255) / 256, 256, 0, stream>>>(W1, Wmu, Wls, WbT, W2T, gcur);

    k_coarse<<<NBLK, 256, 0, stream>>>(src, dstp, gcur, cpair, E);
    k_fine<<<NB2, 256, 0, stream>>>(cpair, gcur, rowoff, dis, esrc);

    k_gemm1<<<(N_NODES + GBM - 1) / GBM, 256, 0, stream>>>(x, WbT, dis, hbuf, N_NODES);

    k_g1g2<<<(N_NODES + FB - 1) / FB, 256, 0, stream>>>(
        (const ushort4*)hbuf, rowoff, esrc, dis, b1, W2T, h23, N_NODES);

    k_gather2<<<(N_NODES + 15) / 16, 256, 0, stream>>>(
        (const ushort4*)h23, rowoff, esrc, dis, bmu, bls, (float4*)d_out);
}

// Round 19
// 140.496 us; speedup vs baseline: 1.2060x; 1.2060x over previous
//
#include <hip/hip_runtime.h>
#include <hip/hip_bf16.h>

#define N_NODES 50000
#define NIN 512
#define NH 96
#define NL 32
#define NH2 64

#define NB2 196          // coarse buckets of 256 nodes
#define NBLK 128         // binning blocks
#define BCAP 5120        // fixed region capacity per bucket (E[cnt]=4096, +16 sigma)

typedef __attribute__((ext_vector_type(8))) short short8v;   // 8 bf16 (4 VGPR)
typedef __attribute__((ext_vector_type(4))) float f32x4;

__device__ __forceinline__ unsigned short f2bf(float f) {    // RNE via native cvt
    __hip_bfloat16 h = __float2bfloat16(f);
    unsigned short u;
    __builtin_memcpy(&u, &h, 2);
    return u;
}
__device__ __forceinline__ float bf2f(unsigned short h) {
    return __uint_as_float((unsigned)h << 16);
}

// fused: WbT = W1^T bf16; W2T = [Wmu|Wls]^T bf16; gcur = 0
__global__ __launch_bounds__(256) void k_prep(const float* __restrict__ W1,
                                              const float* __restrict__ Wmu,
                                              const float* __restrict__ Wls,
                                              unsigned short* __restrict__ WbT,
                                              unsigned short* __restrict__ W2T,
                                              int* __restrict__ gcur) {
    int idx = blockIdx.x * 256 + threadIdx.x;
    if (idx < NH * NIN) {
        int n = idx >> 9, k = idx & 511;
        WbT[idx] = f2bf(W1[(size_t)k * NH + n]);
    } else if (idx < NH * NIN + NH2 * NH) {
        int j = idx - NH * NIN;
        int n = j / NH, k = j - n * NH;
        float v = (n < NL) ? Wmu[k * NL + n] : Wls[k * NL + (n - NL)];
        W2T[j] = f2bf(v);
    }
    if (idx < NB2) gcur[idx] = 0;
}

// pass A: privatized block-run binning into fixed-capacity bucket regions.
// Runs contiguous -> each cache line owned by one block/XCD (r14 lesson).
__global__ __launch_bounds__(256) void k_coarse(const int* __restrict__ src,
                                                const int* __restrict__ dst,
                                                int* __restrict__ gcur,
                                                unsigned* __restrict__ cpair, int E) {
    __shared__ int hist[NB2];
    __shared__ int lpos[NB2];
    int t = threadIdx.x;
    int ch = (E + NBLK - 1) / NBLK;
    int e0 = blockIdx.x * ch, e1 = min(e0 + ch, E);
    for (int b = t; b < NB2; b += 256) hist[b] = 0;
    __syncthreads();
    for (int e = e0 + t; e < e1; e += 256)
        atomicAdd(&hist[dst[e] >> 8], 1);
    __syncthreads();
    for (int b = t; b < NB2; b += 256) {
        int cnt = hist[b];
        int base = (cnt > 0) ? atomicAdd(&gcur[b], cnt) : 0;
        lpos[b] = b * BCAP + base;
    }
    __syncthreads();
    for (int e = e0 + t; e < e1; e += 256) {
        int s = src[e], d = dst[e];
        int pos = atomicAdd(&lpos[d >> 8], 1);
        cpair[pos] = (unsigned)s | ((unsigned)d << 16);
    }
}

// pass B: one block per bucket. Computes its own global base (LDS reduce over
// gcur[0..bb-1]), derives per-node counts + rowoff + dis, then places edges
// into the bucket's private esrc window.
__global__ __launch_bounds__(256) void k_fine(const unsigned* __restrict__ cpair,
                                              const int* __restrict__ gcur,
                                              int* __restrict__ rowoff,
                                              float* __restrict__ dis,
                                              int* __restrict__ esrc) {
    __shared__ int lcnt[256];
    __shared__ int lscan[256];
    int bb = blockIdx.x;
    int n0 = bb << 8;
    int t = threadIdx.x;
    // base = sum gcur[0..bb-1]
    lscan[t] = (t < bb) ? gcur[t] : 0;
    __syncthreads();
    for (int off = 128; off > 0; off >>= 1) {
        if (t < off) lscan[t] += lscan[t + off];
        __syncthreads();
    }
    int base = lscan[0];
    if (bb == NB2 - 1 && t == 0) rowoff[N_NODES] = base + gcur[bb];
    lcnt[t] = 0;
    __syncthreads();
    int p0 = bb * BCAP;
    int p1 = p0 + gcur[bb];
    for (int p = p0 + t; p < p1; p += 256)
        atomicAdd(&lcnt[(cpair[p] >> 16) - n0], 1);
    __syncthreads();
    int cnt = lcnt[t];
    lscan[t] = cnt;
    __syncthreads();
    for (int off = 1; off < 256; off <<= 1) {
        int u = (t >= off) ? lscan[t - off] : 0;
        __syncthreads();
        lscan[t] += u;
        __syncthreads();
    }
    int excl = lscan[t] - cnt;
    int node = n0 + t;
    if (node < N_NODES) {
        rowoff[node] = base + excl;
        dis[node] = rsqrtf((float)cnt + 1.0f);
    }
    lcnt[t] = base + excl;
    __syncthreads();
    for (int p = p0 + t; p < p1; p += 256) {
        unsigned u = cpair[p];
        int d = (int)(u >> 16);
        int pos = atomicAdd(&lcnt[d - n0], 1);
        esrc[pos] = (int)(u & 0xFFFFu);
    }
}

// h' = (x @ W1) * dis[row], bf16 MFMA 16x16x32 (r16 measured-best config).
// BM=64 (4 waves x 16 rows), BK=64, 8 K-tiles -> 782 blocks = 3 blocks/CU.
// LDS rows 128B, slot ^= (row&7): conflict-free frag reads, coalesced staging.
#define GBM 64
__global__ __launch_bounds__(256, 3) void k_gemm1(const float* __restrict__ x,
                                                  const unsigned short* __restrict__ WbT,
                                                  const float* __restrict__ dis,
                                                  unsigned short* __restrict__ hb, int M) {
    __shared__ __align__(16) char lA[64 * 128];    // 8 KB
    __shared__ __align__(16) char lB[96 * 128];    // 12 KB
    int tid = threadIdx.x;
    int lane = tid & 63, w = tid >> 6;
    int l15 = lane & 15, hi = lane >> 4;
    int m0 = blockIdx.x * GBM;

    f32x4 acc[6];
#pragma unroll
    for (int nt = 0; nt < 6; ++nt)
#pragma unroll
        for (int i = 0; i < 4; ++i) acc[nt][i] = 0.f;

    int key = l15 & 7;
    int arow = (w * 16 + l15) * 128;

    for (int kt = 0; kt < 8; ++kt) {
        __syncthreads();
#pragma unroll
        for (int i = 0; i < 2; ++i) {      // A: 512 slots (64 rows x 8), 2/thread
            int s = i * 256 + tid;
            int r = s >> 3, sl = s & 7;
            const float* p = x + (size_t)min(m0 + r, M - 1) * NIN + kt * 64 + sl * 8;
            float4 a0 = *reinterpret_cast<const float4*>(p);
            float4 a1 = *reinterpret_cast<const float4*>(p + 4);
            uint4 pk;
            pk.x = (unsigned)f2bf(a0.x) | ((unsigned)f2bf(a0.y) << 16);
            pk.y = (unsigned)f2bf(a0.z) | ((unsigned)f2bf(a0.w) << 16);
            pk.z = (unsigned)f2bf(a1.x) | ((unsigned)f2bf(a1.y) << 16);
            pk.w = (unsigned)f2bf(a1.z) | ((unsigned)f2bf(a1.w) << 16);
            *reinterpret_cast<uint4*>(lA + r * 128 + ((sl ^ (r & 7)) << 4)) = pk;
        }
#pragma unroll
        for (int i = 0; i < 3; ++i) {      // B: 768 slots (96 rows x 8), 3/thread
            int s = i * 256 + tid;
            int n = s >> 3, sl = s & 7;
            uint4 bv = *reinterpret_cast<const uint4*>(WbT + (size_t)n * NIN + kt * 64 + sl * 8);
            *reinterpret_cast<uint4*>(lB + n * 128 + ((sl ^ (n & 7)) << 4)) = bv;
        }
        __syncthreads();

#pragma unroll
        for (int kc = 0; kc < 2; ++kc) {
            int off = (((kc * 4 + hi) ^ key) << 4);
            short8v a = *reinterpret_cast<const short8v*>(lA + arow + off);
#pragma unroll
            for (int nt = 0; nt < 6; ++nt) {
                short8v bv = *reinterpret_cast<const short8v*>(lB + (nt * 16 + l15) * 128 + off);
                acc[nt] = __builtin_amdgcn_mfma_f32_16x16x32_bf16(a, bv, acc[nt], 0, 0, 0);
            }
        }
    }

    // C: row=(lane>>4)*4+reg, col=lane&15 (m89-verified); fuse dis scale, bf16 out
    int rbase = m0 + w * 16 + hi * 4;
#pragma unroll
    for (int r = 0; r < 4; ++r) {
        int orow = rbase + r;
        if (orow < M) {
            float dv = dis[orow];
            unsigned short* op = hb + (size_t)orow * NH + l15;
#pragma unroll
            for (int nt = 0; nt < 6; ++nt) op[nt * 16] = f2bf(acc[nt][r] * dv);
        }
    }
}

// gather layer 1 (bf16 rows, 192B): hid = relu((sum h'[s] + h'[i]) * dis + b1)
// r17 measured form: 6250 blocks (24/CU) -- the TLP is what hides the random
// row-fetch latency (r18's 782-block fusion collapsed it: 142->169 regression).
__global__ __launch_bounds__(256) void k_gather1(const ushort4* __restrict__ hb4,
                                                 const int* __restrict__ rowoff,
                                                 const int* __restrict__ esrc,
                                                 const float* __restrict__ dis,
                                                 const float* __restrict__ b1,
                                                 ushort4* __restrict__ hid4) {
    int tid = threadIdx.x;
    int node = blockIdx.x * 8 + (tid >> 5);
    int c = tid & 31;
    if (node >= N_NODES) return;
    int p0 = rowoff[node], p1 = rowoff[node + 1];
    bool act = (c < 24);
    float ax = 0.f, ay = 0.f, az = 0.f, aw = 0.f;
    for (int pb = p0; pb < p1; pb += 32) {
        int nb = min(32, p1 - pb);
        int sv = (c < nb) ? esrc[pb + c] : 0;
#pragma unroll 4
        for (int j = 0; j < nb; j++) {
            int s = __shfl(sv, j, 32);
            if (act) {
                ushort4 v = hb4[(size_t)s * 24 + c];
                ax += bf2f(v.x); ay += bf2f(v.y); az += bf2f(v.z); aw += bf2f(v.w);
            }
        }
    }
    if (act) {
        float dv = dis[node];
        ushort4 hv = hb4[(size_t)node * 24 + c];
        float4 bv = reinterpret_cast<const float4*>(b1)[c];
        ushort4 o;
        o.x = f2bf(fmaxf((ax + bf2f(hv.x)) * dv + bv.x, 0.f));
        o.y = f2bf(fmaxf((ay + bf2f(hv.y)) * dv + bv.y, 0.f));
        o.z = f2bf(fmaxf((az + bf2f(hv.z)) * dv + bv.z, 0.f));
        o.w = f2bf(fmaxf((aw + bf2f(hv.w)) * dv + bv.w, 0.f));
        hid4[(size_t)node * 24 + c] = o;
    }
}

// h23' = (hid @ W2) * dis[row], bf16 MFMA with LDS staging (r17 verified form).
#define GBM2 64
__global__ __launch_bounds__(256) void k_gemm2(const unsigned short* __restrict__ hid,
                                               const unsigned short* __restrict__ W2T,
                                               const float* __restrict__ dis,
                                               unsigned short* __restrict__ h23, int M) {
    __shared__ __align__(16) char lA[64 * 256];    // 16 KB (12/16 slots used)
    __shared__ __align__(16) char lB[64 * 256];    // 16 KB
    int tid = threadIdx.x;
    int lane = tid & 63, w = tid >> 6;
    int l15 = lane & 15, hi = lane >> 4;
    int m0 = blockIdx.x * GBM2;

#pragma unroll
    for (int i = 0; i < 3; ++i) {
        int s = i * 256 + tid;
        int r = s / 12, sl = s - r * 12;
        uint4 v = *reinterpret_cast<const uint4*>(
            hid + (size_t)min(m0 + r, M - 1) * NH + sl * 8);
        *reinterpret_cast<uint4*>(lA + r * 256 + ((sl ^ (r & 7)) << 4)) = v;
    }
#pragma unroll
    for (int i = 0; i < 3; ++i) {
        int s = i * 256 + tid;
        int n = s / 12, sl = s - n * 12;
        uint4 v = *reinterpret_cast<const uint4*>(W2T + (size_t)n * NH + sl * 8);
        *reinterpret_cast<uint4*>(lB + n * 256 + ((sl ^ (n & 7)) << 4)) = v;
    }
    __syncthreads();

    f32x4 acc[4];
#pragma unroll
    for (int nt = 0; nt < 4; ++nt)
#pragma unroll
        for (int i = 0; i < 4; ++i) acc[nt][i] = 0.f;

    int key = l15 & 7;
    const char* aptr = lA + (w * 16 + l15) * 256;
#pragma unroll
    for (int kc = 0; kc < 3; ++kc) {
        int off = (((kc * 4 + hi) ^ key) << 4);
        short8v a = *reinterpret_cast<const short8v*>(aptr + off);
#pragma unroll
        for (int nt = 0; nt < 4; ++nt) {
            short8v bv = *reinterpret_cast<const short8v*>(lB + (nt * 16 + l15) * 256 + off);
            acc[nt] = __builtin_amdgcn_mfma_f32_16x16x32_bf16(a, bv, acc[nt], 0, 0, 0);
        }
    }

    int rbase = m0 + w * 16 + hi * 4;
#pragma unroll
    for (int r = 0; r < 4; ++r) {
        int orow = rbase + r;
        if (orow < M) {
            float dv = dis[orow];
            unsigned short* op = h23 + (size_t)orow * NH2 + l15;
#pragma unroll
            for (int nt = 0; nt < 4; ++nt) op[nt * 16] = f2bf(acc[nt][r] * dv);
        }
    }
}

// gather layer 2 (bf16 rows, 128B): out = (sum h23'[s] + h23'[i]) * dis + bias
__global__ __launch_bounds__(256) void k_gather2(const ushort4* __restrict__ hb4,
                                                 const int* __restrict__ rowoff,
                                                 const int* __restrict__ esrc,
                                                 const float* __restrict__ dis,
                                                 const float* __restrict__ bmu,
                                                 const float* __restrict__ bls,
                                                 float4* __restrict__ out4) {
    int tid = threadIdx.x;
    int node = blockIdx.x * 16 + (tid >> 4);
    int c = tid & 15;
    if (node >= N_NODES) return;
    int p0 = rowoff[node], p1 = rowoff[node + 1];
    float ax = 0.f, ay = 0.f, az = 0.f, aw = 0.f;
    for (int pb = p0; pb < p1; pb += 16) {
        int nb = min(16, p1 - pb);
        int sv = (c < nb) ? esrc[pb + c] : 0;
#pragma unroll 4
        for (int j = 0; j < nb; j++) {
            int s = __shfl(sv, j, 16);
            ushort4 v = hb4[(size_t)s * 16 + c];
            ax += bf2f(v.x); ay += bf2f(v.y); az += bf2f(v.z); aw += bf2f(v.w);
        }
    }
    float dv = dis[node];
    ushort4 hv = hb4[(size_t)node * 16 + c];
    float4 bv = (c < 8) ? reinterpret_cast<const float4*>(bmu)[c]
                        : reinterpret_cast<const float4*>(bls)[c - 8];
    float4 o;
    o.x = (ax + bf2f(hv.x)) * dv + bv.x;
    o.y = (ay + bf2f(hv.y)) * dv + bv.y;
    o.z = (az + bf2f(hv.z)) * dv + bv.z;
    o.w = (aw + bf2f(hv.w)) * dv + bv.w;
    if (c < 8) out4[(size_t)node * 8 + c] = o;
    else       out4[(size_t)N_NODES * 8 + (size_t)node * 8 + (c - 8)] = o;
}

extern "C" void kernel_launch(void* const* d_in, const int* in_sizes, int n_in,
                              void* d_out, int out_size, void* d_ws, size_t ws_size,
                              hipStream_t stream) {
    const float* x   = (const float*)d_in[0];
    const float* W1  = (const float*)d_in[1];
    const float* b1  = (const float*)d_in[2];
    const float* Wmu = (const float*)d_in[3];
    const float* bmu = (const float*)d_in[4];
    const float* Wls = (const float*)d_in[5];
    const float* bls = (const float*)d_in[6];
    const int*   ei  = (const int*)d_in[7];
    int E = in_sizes[7] / 2;
    const int* src  = ei;
    const int* dstp = ei + E;

    char* w = (char*)d_ws;
    int* rowoff  = (int*)w;            w += ((size_t)N_NODES + 4) * 4;
    float* dis   = (float*)w;          w += (size_t)N_NODES * 4;
    int* gcur    = (int*)w;            w += ((size_t)NB2 + 4) * 4;
    int* esrc    = (int*)w;            w += (size_t)E * 4;
    unsigned* cpair = (unsigned*)w;    w += (size_t)NB2 * BCAP * 4;
    unsigned short* WbT  = (unsigned short*)w;  w += (size_t)NH * NIN * 2;
    unsigned short* W2T  = (unsigned short*)w;  w += (size_t)NH2 * NH * 2;
    unsigned short* hbuf = (unsigned short*)w;  w += (size_t)N_NODES * NH * 2;
    unsigned short* hid  = (unsigned short*)w;  w += (size_t)N_NODES * NH * 2;
    unsigned short* h23  = (unsigned short*)w;  w += (size_t)N_NODES * NH2 * 2;

    int prep_n = NH * NIN + NH2 * NH;
    k_prep<<<(prep_n + 255) / 256, 256, 0, stream>>>(W1, Wmu, Wls, WbT, W2T, gcur);

    k_coarse<<<NBLK, 256, 0, stream>>>(src, dstp, gcur, cpair, E);
    k_fine<<<NB2, 256, 0, stream>>>(cpair, gcur, rowoff, dis, esrc);

    k_gemm1<<<(N_NODES + GBM - 1) / GBM, 256, 0, stream>>>(x, WbT, dis, hbuf, N_NODES);

    k_gather1<<<(N_NODES + 7) / 8, 256, 0, stream>>>(
        (const ushort4*)hbuf, rowoff, esrc, dis, b1, (ushort4*)hid);

    k_gemm2<<<(N_NODES + GBM2 - 1) / GBM2, 256, 0, stream>>>(hid, W2T, dis, h23, N_NODES);

    k_gather2<<<(N_NODES + 15) / 16, 256, 0, stream>>>(
        (const ushort4*)h23, rowoff, esrc, dis, bmu, bls, (float4*)d_out);
}

// Round 20
// 120.556 us; speedup vs baseline: 1.4055x; 1.1654x over previous
//
#include <hip/hip_runtime.h>
#include <hip/hip_bf16.h>

#define N_NODES 50000
#define NIN 512
#define NH 96
#define NL 32
#define NH2 64

#define NB2 196          // coarse buckets of 256 nodes
#define NBLK 128         // binning blocks
#define BCAP 5120        // fixed region capacity per bucket (E[cnt]=4096, +16 sigma)
#define ECH 6250         // edges per coarse block (800000/128)

typedef __attribute__((ext_vector_type(8))) short short8v;   // 8 bf16 (4 VGPR)
typedef __attribute__((ext_vector_type(4))) float f32x4;

__device__ __forceinline__ unsigned short f2bf(float f) {    // RNE via native cvt
    __hip_bfloat16 h = __float2bfloat16(f);
    unsigned short u;
    __builtin_memcpy(&u, &h, 2);
    return u;
}
__device__ __forceinline__ float bflo(unsigned u) { return __uint_as_float(u << 16); }
__device__ __forceinline__ float bfhi(unsigned u) { return __uint_as_float(u & 0xFFFF0000u); }
__device__ __forceinline__ float bf2f(unsigned short h) {
    return __uint_as_float((unsigned)h << 16);
}

// fused: WbT = W1^T bf16; W2T = [Wmu|Wls]^T bf16; gcur = 0
__global__ __launch_bounds__(256) void k_prep(const float* __restrict__ W1,
                                              const float* __restrict__ Wmu,
                                              const float* __restrict__ Wls,
                                              unsigned short* __restrict__ WbT,
                                              unsigned short* __restrict__ W2T,
                                              int* __restrict__ gcur) {
    int idx = blockIdx.x * 256 + threadIdx.x;
    if (idx < NH * NIN) {
        int n = idx >> 9, k = idx & 511;
        WbT[idx] = f2bf(W1[(size_t)k * NH + n]);
    } else if (idx < NH * NIN + NH2 * NH) {
        int j = idx - NH * NIN;
        int n = j / NH, k = j - n * NH;
        float v = (n < NL) ? Wmu[k * NL + n] : Wls[k * NL + (n - NL)];
        W2T[j] = f2bf(v);
    }
    if (idx < NB2) gcur[idx] = 0;
}

// pass A: privatized block-run binning; packed pairs cached in LDS during the
// histogram pass so placement re-reads LDS, not global src/dst (r19 trim).
// Runs contiguous -> each cache line owned by one block/XCD (r14 lesson).
__global__ __launch_bounds__(256) void k_coarse(const int* __restrict__ src,
                                                const int* __restrict__ dst,
                                                int* __restrict__ gcur,
                                                unsigned* __restrict__ cpair, int E) {
    __shared__ unsigned epk[ECH];
    __shared__ int hist[NB2];
    __shared__ int lpos[NB2];
    int t = threadIdx.x;
    int ch = (E + NBLK - 1) / NBLK;      // == ECH for E=800000
    int e0 = blockIdx.x * ch, e1 = min(e0 + ch, E);
    int n = e1 - e0;
    for (int b = t; b < NB2; b += 256) hist[b] = 0;
    __syncthreads();
    for (int li = t; li < n; li += 256) {
        int s = src[e0 + li], d = dst[e0 + li];
        epk[li] = (unsigned)s | ((unsigned)d << 16);
        atomicAdd(&hist[d >> 8], 1);
    }
    __syncthreads();
    for (int b = t; b < NB2; b += 256) {
        int cnt = hist[b];
        int base = (cnt > 0) ? atomicAdd(&gcur[b], cnt) : 0;
        lpos[b] = b * BCAP + base;
    }
    __syncthreads();
    for (int li = t; li < n; li += 256) {
        unsigned u = epk[li];
        int pos = atomicAdd(&lpos[u >> 24], 1);   // (d>>8) == (u>>16)>>8 == u>>24
        cpair[pos] = u;
    }
}

// pass B: one block per bucket. Computes its own global base (LDS reduce over
// gcur[0..bb-1]), derives per-node counts + rowoff + dis, then places edges
// into the bucket's private esrc window.
__global__ __launch_bounds__(256) void k_fine(const unsigned* __restrict__ cpair,
                                              const int* __restrict__ gcur,
                                              int* __restrict__ rowoff,
                                              float* __restrict__ dis,
                                              int* __restrict__ esrc) {
    __shared__ int lcnt[256];
    __shared__ int lscan[256];
    int bb = blockIdx.x;
    int n0 = bb << 8;
    int t = threadIdx.x;
    lscan[t] = (t < bb) ? gcur[t] : 0;
    __syncthreads();
    for (int off = 128; off > 0; off >>= 1) {
        if (t < off) lscan[t] += lscan[t + off];
        __syncthreads();
    }
    int base = lscan[0];
    if (bb == NB2 - 1 && t == 0) rowoff[N_NODES] = base + gcur[bb];
    lcnt[t] = 0;
    __syncthreads();
    int p0 = bb * BCAP;
    int p1 = p0 + gcur[bb];
    for (int p = p0 + t; p < p1; p += 256)
        atomicAdd(&lcnt[(cpair[p] >> 16) - n0], 1);
    __syncthreads();
    int cnt = lcnt[t];
    lscan[t] = cnt;
    __syncthreads();
    for (int off = 1; off < 256; off <<= 1) {
        int u = (t >= off) ? lscan[t - off] : 0;
        __syncthreads();
        lscan[t] += u;
        __syncthreads();
    }
    int excl = lscan[t] - cnt;
    int node = n0 + t;
    if (node < N_NODES) {
        rowoff[node] = base + excl;
        dis[node] = rsqrtf((float)cnt + 1.0f);
    }
    lcnt[t] = base + excl;
    __syncthreads();
    for (int p = p0 + t; p < p1; p += 256) {
        unsigned u = cpair[p];
        int d = (int)(u >> 16);
        int pos = atomicAdd(&lcnt[d - n0], 1);
        esrc[pos] = (int)(u & 0xFFFFu);
    }
}

// h' = (x @ W1) * dis[row], bf16 MFMA 16x16x32.
// BM=64 (4 waves x 16 rows), BK=128 -> 4 K-tiles (barriers 16->8 vs r16),
// still 3 blocks/CU (40KB LDS, launch_bounds(256,3): VGPR cap ~170, no spill).
// LDS rows 256B = 16 slots of 16B; slot ^= (row&7) in-row bijective, frag
// reads 2-way (free), staging coalesced.
#define GBM 64
__global__ __launch_bounds__(256, 3) void k_gemm1(const float* __restrict__ x,
                                                  const unsigned short* __restrict__ WbT,
                                                  const float* __restrict__ dis,
                                                  unsigned short* __restrict__ hb, int M) {
    __shared__ __align__(16) char lA[64 * 256];    // 16 KB
    __shared__ __align__(16) char lB[96 * 256];    // 24 KB
    int tid = threadIdx.x;
    int lane = tid & 63, w = tid >> 6;
    int l15 = lane & 15, hi = lane >> 4;
    int m0 = blockIdx.x * GBM;

    f32x4 acc[6];
#pragma unroll
    for (int nt = 0; nt < 6; ++nt)
#pragma unroll
        for (int i = 0; i < 4; ++i) acc[nt][i] = 0.f;

    int key = l15 & 7;
    int arow = (w * 16 + l15) * 256;

    for (int kt = 0; kt < 4; ++kt) {
        __syncthreads();
#pragma unroll
        for (int i = 0; i < 4; ++i) {      // A: 1024 slots (64 rows x 16), 4/thread
            int s = i * 256 + tid;
            int r = s >> 4, sl = s & 15;
            const float* p = x + (size_t)min(m0 + r, M - 1) * NIN + kt * 128 + sl * 8;
            float4 a0 = *reinterpret_cast<const float4*>(p);
            float4 a1 = *reinterpret_cast<const float4*>(p + 4);
            uint4 pk;
            pk.x = (unsigned)f2bf(a0.x) | ((unsigned)f2bf(a0.y) << 16);
            pk.y = (unsigned)f2bf(a0.z) | ((unsigned)f2bf(a0.w) << 16);
            pk.z = (unsigned)f2bf(a1.x) | ((unsigned)f2bf(a1.y) << 16);
            pk.w = (unsigned)f2bf(a1.z) | ((unsigned)f2bf(a1.w) << 16);
            *reinterpret_cast<uint4*>(lA + r * 256 + ((sl ^ (r & 7)) << 4)) = pk;
        }
#pragma unroll
        for (int i = 0; i < 6; ++i) {      // B: 1536 slots (96 rows x 16), 6/thread
            int s = i * 256 + tid;
            int n = s >> 4, sl = s & 15;
            uint4 bv = *reinterpret_cast<const uint4*>(WbT + (size_t)n * NIN + kt * 128 + sl * 8);
            *reinterpret_cast<uint4*>(lB + n * 256 + ((sl ^ (n & 7)) << 4)) = bv;
        }
        __syncthreads();

#pragma unroll
        for (int kc = 0; kc < 4; ++kc) {
            int off = (((kc * 4 + hi) ^ key) << 4);
            short8v a = *reinterpret_cast<const short8v*>(lA + arow + off);
#pragma unroll
            for (int nt = 0; nt < 6; ++nt) {
                short8v bv = *reinterpret_cast<const short8v*>(lB + (nt * 16 + l15) * 256 + off);
                acc[nt] = __builtin_amdgcn_mfma_f32_16x16x32_bf16(a, bv, acc[nt], 0, 0, 0);
            }
        }
    }

    // C: row=(lane>>4)*4+reg, col=lane&15 (m89-verified); fuse dis scale, bf16 out
    int rbase = m0 + w * 16 + hi * 4;
#pragma unroll
    for (int r = 0; r < 4; ++r) {
        int orow = rbase + r;
        if (orow < M) {
            float dv = dis[orow];
            unsigned short* op = hb + (size_t)orow * NH + l15;
#pragma unroll
            for (int nt = 0; nt < 6; ++nt) op[nt * 16] = f2bf(acc[nt][r] * dv);
        }
    }
}

// gather layer 1: hid = relu((sum h'[s] + h'[i]) * dis + b1).
// 16-lane groups, 12 active lanes x uint4 (16B) per 192B row -> 4 independent
// node-streams per wave (2x the r17 MLP; same bytes, same lane activity).
__global__ __launch_bounds__(256) void k_gather1(const uint4* __restrict__ hb4,
                                                 const int* __restrict__ rowoff,
                                                 const int* __restrict__ esrc,
                                                 const float* __restrict__ dis,
                                                 const float* __restrict__ b1,
                                                 uint4* __restrict__ hid4) {
    int tid = threadIdx.x;
    int node = blockIdx.x * 16 + (tid >> 4);
    int c = tid & 15;
    if (node >= N_NODES) return;
    int p0 = rowoff[node], p1 = rowoff[node + 1];
    bool act = (c < 12);
    float a0 = 0.f, a1 = 0.f, a2 = 0.f, a3 = 0.f;
    float a4 = 0.f, a5 = 0.f, a6 = 0.f, a7 = 0.f;
    for (int pb = p0; pb < p1; pb += 16) {
        int nb = min(16, p1 - pb);
        int sv = (c < nb) ? esrc[pb + c] : 0;
#pragma unroll 4
        for (int j = 0; j < nb; j++) {
            int s = __shfl(sv, j, 16);
            if (act) {
                uint4 v = hb4[(size_t)s * 12 + c];
                a0 += bflo(v.x); a1 += bfhi(v.x);
                a2 += bflo(v.y); a3 += bfhi(v.y);
                a4 += bflo(v.z); a5 += bfhi(v.z);
                a6 += bflo(v.w); a7 += bfhi(v.w);
            }
        }
    }
    if (act) {
        float dv = dis[node];
        uint4 hv = hb4[(size_t)node * 12 + c];
        float4 b0 = reinterpret_cast<const float4*>(b1)[c * 2];
        float4 b4 = reinterpret_cast<const float4*>(b1)[c * 2 + 1];
        float r0 = fmaxf((a0 + bflo(hv.x)) * dv + b0.x, 0.f);
        float r1 = fmaxf((a1 + bfhi(hv.x)) * dv + b0.y, 0.f);
        float r2 = fmaxf((a2 + bflo(hv.y)) * dv + b0.z, 0.f);
        float r3 = fmaxf((a3 + bfhi(hv.y)) * dv + b0.w, 0.f);
        float r4 = fmaxf((a4 + bflo(hv.z)) * dv + b4.x, 0.f);
        float r5 = fmaxf((a5 + bfhi(hv.z)) * dv + b4.y, 0.f);
        float r6 = fmaxf((a6 + bflo(hv.w)) * dv + b4.z, 0.f);
        float r7 = fmaxf((a7 + bfhi(hv.w)) * dv + b4.w, 0.f);
        uint4 o;
        o.x = (unsigned)f2bf(r0) | ((unsigned)f2bf(r1) << 16);
        o.y = (unsigned)f2bf(r2) | ((unsigned)f2bf(r3) << 16);
        o.z = (unsigned)f2bf(r4) | ((unsigned)f2bf(r5) << 16);
        o.w = (unsigned)f2bf(r6) | ((unsigned)f2bf(r7) << 16);
        hid4[(size_t)node * 12 + c] = o;
    }
}

// h23' = (hid @ W2) * dis[row], bf16 MFMA with LDS staging (r17 verified form).
#define GBM2 64
__global__ __launch_bounds__(256) void k_gemm2(const unsigned short* __restrict__ hid,
                                               const unsigned short* __restrict__ W2T,
                                               const float* __restrict__ dis,
                                               unsigned short* __restrict__ h23, int M) {
    __shared__ __align__(16) char lA[64 * 256];    // 16 KB (12/16 slots used)
    __shared__ __align__(16) char lB[64 * 256];    // 16 KB
    int tid = threadIdx.x;
    int lane = tid & 63, w = tid >> 6;
    int l15 = lane & 15, hi = lane >> 4;
    int m0 = blockIdx.x * GBM2;

#pragma unroll
    for (int i = 0; i < 3; ++i) {
        int s = i * 256 + tid;
        int r = s / 12, sl = s - r * 12;
        uint4 v = *reinterpret_cast<const uint4*>(
            hid + (size_t)min(m0 + r, M - 1) * NH + sl * 8);
        *reinterpret_cast<uint4*>(lA + r * 256 + ((sl ^ (r & 7)) << 4)) = v;
    }
#pragma unroll
    for (int i = 0; i < 3; ++i) {
        int s = i * 256 + tid;
        int n = s / 12, sl = s - n * 12;
        uint4 v = *reinterpret_cast<const uint4*>(W2T + (size_t)n * NH + sl * 8);
        *reinterpret_cast<uint4*>(lB + n * 256 + ((sl ^ (n & 7)) << 4)) = v;
    }
    __syncthreads();

    f32x4 acc[4];
#pragma unroll
    for (int nt = 0; nt < 4; ++nt)
#pragma unroll
        for (int i = 0; i < 4; ++i) acc[nt][i] = 0.f;

    int key = l15 & 7;
    const char* aptr = lA + (w * 16 + l15) * 256;
#pragma unroll
    for (int kc = 0; kc < 3; ++kc) {
        int off = (((kc * 4 + hi) ^ key) << 4);
        short8v a = *reinterpret_cast<const short8v*>(aptr + off);
#pragma unroll
        for (int nt = 0; nt < 4; ++nt) {
            short8v bv = *reinterpret_cast<const short8v*>(lB + (nt * 16 + l15) * 256 + off);
            acc[nt] = __builtin_amdgcn_mfma_f32_16x16x32_bf16(a, bv, acc[nt], 0, 0, 0);
        }
    }

    int rbase = m0 + w * 16 + hi * 4;
#pragma unroll
    for (int r = 0; r < 4; ++r) {
        int orow = rbase + r;
        if (orow < M) {
            float dv = dis[orow];
            unsigned short* op = h23 + (size_t)orow * NH2 + l15;
#pragma unroll
            for (int nt = 0; nt < 4; ++nt) op[nt * 16] = f2bf(acc[nt][r] * dv);
        }
    }
}

// gather layer 2: out = (sum h23'[s] + h23'[i]) * dis + bias, split mu/logstd.
// 8-lane groups x uint4 (16B) per 128B row, all lanes active -> 8 node-streams
// per wave (4x the r17 MLP).
__global__ __launch_bounds__(256) void k_gather2(const uint4* __restrict__ hb4,
                                                 const int* __restrict__ rowoff,
                                                 const int* __restrict__ esrc,
                                                 const float* __restrict__ dis,
                                                 const float* __restrict__ bmu,
                                                 const float* __restrict__ bls,
                                                 float4* __restrict__ out4) {
    int tid = threadIdx.x;
    int node = blockIdx.x * 32 + (tid >> 3);
    int c = tid & 7;
    if (node >= N_NODES) return;
    int p0 = rowoff[node], p1 = rowoff[node + 1];
    float a0 = 0.f, a1 = 0.f, a2 = 0.f, a3 = 0.f;
    float a4 = 0.f, a5 = 0.f, a6 = 0.f, a7 = 0.f;
    for (int pb = p0; pb < p1; pb += 8) {
        int nb = min(8, p1 - pb);
        int sv = (c < nb) ? esrc[pb + c] : 0;
#pragma unroll 4
        for (int j = 0; j < nb; j++) {
            int s = __shfl(sv, j, 8);
            uint4 v = hb4[(size_t)s * 8 + c];
            a0 += bflo(v.x); a1 += bfhi(v.x);
            a2 += bflo(v.y); a3 += bfhi(v.y);
            a4 += bflo(v.z); a5 += bfhi(v.z);
            a6 += bflo(v.w); a7 += bfhi(v.w);
        }
    }
    float dv = dis[node];
    uint4 hv = hb4[(size_t)node * 8 + c];
    const float4* bp = (c < 4) ? reinterpret_cast<const float4*>(bmu) + c * 2
                               : reinterpret_cast<const float4*>(bls) + (c - 4) * 2;
    float4 b0 = bp[0], b4 = bp[1];
    float4 o0, o1;
    o0.x = (a0 + bflo(hv.x)) * dv + b0.x;
    o0.y = (a1 + bfhi(hv.x)) * dv + b0.y;
    o0.z = (a2 + bflo(hv.y)) * dv + b0.z;
    o0.w = (a3 + bfhi(hv.y)) * dv + b0.w;
    o1.x = (a4 + bflo(hv.z)) * dv + b4.x;
    o1.y = (a5 + bfhi(hv.z)) * dv + b4.y;
    o1.z = (a6 + bflo(hv.w)) * dv + b4.z;
    o1.w = (a7 + bfhi(hv.w)) * dv + b4.w;
    size_t base = (c < 4) ? (size_t)node * 8 + c * 2
                          : (size_t)N_NODES * 8 + (size_t)node * 8 + (c - 4) * 2;
    out4[base] = o0;
    out4[base + 1] = o1;
}

extern "C" void kernel_launch(void* const* d_in, const int* in_sizes, int n_in,
                              void* d_out, int out_size, void* d_ws, size_t ws_size,
                              hipStream_t stream) {
    const float* x   = (const float*)d_in[0];
    const float* W1  = (const float*)d_in[1];
    const float* b1  = (const float*)d_in[2];
    const float* Wmu = (const float*)d_in[3];
    const float* bmu = (const float*)d_in[4];
    const float* Wls = (const float*)d_in[5];
    const float* bls = (const float*)d_in[6];
    const int*   ei  = (const int*)d_in[7];
    int E = in_sizes[7] / 2;
    const int* src  = ei;
    const int* dstp = ei + E;

    char* w = (char*)d_ws;
    int* rowoff  = (int*)w;            w += ((size_t)N_NODES + 4) * 4;
    float* dis   = (float*)w;          w += (size_t)N_NODES * 4;
    int* gcur    = (int*)w;            w += ((size_t)NB2 + 4) * 4;
    int* esrc    = (int*)w;            w += (size_t)E * 4;
    unsigned* cpair = (unsigned*)w;    w += (size_t)NB2 * BCAP * 4;
    unsigned short* WbT  = (unsigned short*)w;  w += (size_t)NH * NIN * 2;
    unsigned short* W2T  = (unsigned short*)w;  w += (size_t)NH2 * NH * 2;
    unsigned short* hbuf = (unsigned short*)w;  w += (size_t)N_NODES * NH * 2;
    unsigned short* hid  = (unsigned short*)w;  w += (size_t)N_NODES * NH * 2;
    unsigned short* h23  = (unsigned short*)w;  w += (size_t)N_NODES * NH2 * 2;

    int prep_n = NH * NIN + NH2 * NH;
    k_prep<<<(prep_n + 255) / 256, 256, 0, stream>>>(W1, Wmu, Wls, WbT, W2T, gcur);

    k_coarse<<<NBLK, 256, 0, stream>>>(src, dstp, gcur, cpair, E);
    k_fine<<<NB2, 256, 0, stream>>>(cpair, gcur, rowoff, dis, esrc);

    k_gemm1<<<(N_NODES + GBM - 1) / GBM, 256, 0, stream>>>(x, WbT, dis, hbuf, N_NODES);

    k_gather1<<<(N_NODES + 15) / 16, 256, 0, stream>>>(
        (const uint4*)hbuf, rowoff, esrc, dis, b1, (uint4*)hid);

    k_gemm2<<<(N_NODES + GBM2 - 1) / GBM2, 256, 0, stream>>>(hid, W2T, dis, h23, N_NODES);

    k_gather2<<<(N_NODES + 31) / 32, 256, 0, stream>>>(
        (const uint4*)h23, rowoff, esrc, dis, bmu, bls, (float4*)d_out);
}